// Round 13
// baseline (95.373 us; speedup 1.0000x reference)
//
#include <hip/hip_runtime.h>
#include <math.h>

// Problem constants (fixed by reference setup_inputs)
#define HH 512
#define WW 512
#define NBATCH 16
#define RV 16                      // float path: output rows per strip
#define FSV (HH/RV)                // 32
#define FSH 5                      // float path: horizontal strips (stride 102)
#define NF (NBATCH*FSH*FSV)        // 2560 float wave tasks (= exactly 10/CU)
#define BSU 13                     // bit path: col strips (64 wide, 40 useful)
#define BSV 4                      // bit path: row bands (128 useful rows)
#define NBT (NBATCH*BSU*BSV)       // 832 bitwise wave tasks (chain 1)
#define NTASK (NF + NBT)           // 3392
#define NSTEP (RV + 23)            // 39 steps per strip
#define FINF  (__builtin_huge_valf())

typedef _Float16 h2 __attribute__((ext_vector_type(2)));

__device__ __forceinline__ float sigf(float x) { return 1.0f / (1.0f + __expf(-x)); }
__device__ __forceinline__ unsigned bpermu(int a, unsigned v) {
    return (unsigned)__builtin_amdgcn_ds_bpermute(a, (int)v);
}
__device__ __forceinline__ h2 h2bits(unsigned u) { return __builtin_bit_cast(h2, u); }
__device__ __forceinline__ unsigned bitsh2(h2 h) { return __builtin_bit_cast(unsigned, h); }
__device__ __forceinline__ h2 hmin2(h2 a, h2 b) { return __builtin_elementwise_min(a, b); }
__device__ __forceinline__ h2 hmax2(h2 a, h2 b) { return __builtin_elementwise_max(a, b); }
// DPP wave shifts (VALU, no LDS pipe); boundary lanes keep own value —
// garbage confined to 12-col strip halo (<=11-col propagation).
__device__ __forceinline__ h2 dpp_prev(h2 v) {
    unsigned u = bitsh2(v);
    return h2bits((unsigned)__builtin_amdgcn_update_dpp((int)u, (int)u, 0x130, 0xF, 0xF, false));
}
__device__ __forceinline__ h2 dpp_next(h2 v) {
    unsigned u = bitsh2(v);
    return h2bits((unsigned)__builtin_amdgcn_update_dpp((int)u, (int)u, 0x138, 0xF, 0xF, false));
}
// Packed col-shift vectors (single v_alignbit_b32 where available).
#if __has_builtin(__builtin_amdgcn_alignbit)
__device__ __forceinline__ h2 lvec2(h2 prev, h2 self) {
    return h2bits(__builtin_amdgcn_alignbit(bitsh2(self), bitsh2(prev), 16));
}
__device__ __forceinline__ h2 rvec2(h2 self, h2 next) {
    return h2bits(__builtin_amdgcn_alignbit(bitsh2(next), bitsh2(self), 16));
}
#else
__device__ __forceinline__ h2 lvec2(h2 prev, h2 self) {
    return h2bits((bitsh2(prev) >> 16) | (bitsh2(self) << 16));
}
__device__ __forceinline__ h2 rvec2(h2 self, h2 next) {
    return h2bits((bitsh2(self) >> 16) | (bitsh2(next) << 16));
}
#endif

// ---------------- float path (chain 0: img=sigmoid(pred), weight=target) ----
// fp16x2-packed morphology; warmup/mid gating proved exact (absmax=0 chain).
// R13: warmup+mid loops FULLY unrolled (s compile-time -> gating ifs fold,
// ring shifts become SSA renames); steady loop unrolled x5 (12KB body, fits
// I-cache; full unroll = 36KB = R3's thrash failure mode). Attacks the ~42
// mov + ~10 branch per step that R12's counter arithmetic exposed (pure VALU
// occupancy only ~25% of issue capacity; waves 3.5x stall-stretched).
template<bool GUARD>
__device__ __forceinline__ void do_strip(
    const float* __restrict__ ip, const float* __restrict__ wp,
    int r0, bool ok0, bool ok1, bool useX, bool useY,
    h2 eclamp, h2 dclamp,
    float* __restrict__ partials, int wid, int lane)
{
    const h2 HP = h2bits(0x7C007C00u);   // +inf pair
    const h2 HN = h2bits(0xFC00FC00u);   // -inf pair
    const h2 HZ = h2bits(0u);

    h2 W[11][3], sk[10];
#pragma unroll
    for (int t = 0; t < 11; ++t) { W[t][0] = HP; W[t][1] = HP; W[t][2] = HP; }
#pragma unroll
    for (int j = 0; j < 10; ++j) sk[j] = HZ;
    float wsx = 0.f, wsy = 0.f, rsx = 0.f, rsy = 0.f;

    // ---- prefetch prologue: img row r0-11, weight row r0 ----
    float2 raw;
    if (!GUARD || (unsigned)(r0 - 11) < (unsigned)HH) raw = *(const float2*)ip;
    ip += WW;
    float2 wnext = *(const float2*)wp;   // weight rows r0..r0+RV-1 always valid
    wp += WW;

// convert last step's prefetched row (row fv)
#define CVTROW(fv)                                                      \
    h2 nv;                                                              \
    {                                                                   \
        if (!GUARD || (unsigned)(fv) < (unsigned)HH) {                  \
            float x = sigf(raw.x); x = ok0 ? x : FINF;                  \
            float y = sigf(raw.y); y = ok1 ? y : FINF;                  \
            nv[0] = (_Float16)x; nv[1] = (_Float16)y;                   \
        } else nv = HP;                                                 \
    }

#define PREFETCH(fnext)                                                 \
    {                                                                   \
        if (!GUARD || (unsigned)(fnext) < (unsigned)HH)                 \
            raw = *(const float2*)ip;                                   \
        ip += WW;                                                       \
    }

#define ALEVEL(t)                                                       \
    {                                                                   \
        W[t][0] = W[t][1]; W[t][1] = W[t][2]; W[t][2] = nr;             \
        h2 a0 = W[t][0], a1 = W[t][1], a2 = W[t][2];                    \
        h2 vmin = hmin2(hmin2(a0, a1), a2);                             \
        h2 pv = dpp_prev(a1), nx = dpp_next(a1);                        \
        h2 lv = lvec2(pv, a1), rv = rvec2(a1, nx);                      \
        h2 e = hmin2(vmin, hmin2(lv, rv));                              \
        nr = hmax2(e, eclamp);                                          \
    }

#define BLEVEL(t, fv)                                                   \
    {                                                                   \
        h2 b0 = W[t+1][0], b1 = W[t+1][1], b2 = W[t+1][2];              \
        if (GUARD) {                                                    \
            if ((unsigned)((fv) - t - 4) >= (unsigned)HH) b0 = HN;      \
            if ((unsigned)((fv) - t - 3) >= (unsigned)HH) b1 = HN;      \
            if ((unsigned)((fv) - t - 2) >= (unsigned)HH) b2 = HN;      \
        }                                                               \
        h2 cm = hmin2(hmax2(hmax2(b0, b1), b2), dclamp);                \
        h2 pv = dpp_prev(cm), nx = dpp_next(cm);                        \
        h2 lv = lvec2(pv, cm), rv = rvec2(cm, nx);                      \
        h2 d = hmax2(cm, hmax2(lv, rv));                                \
        h2 df = hmax2(W[t][0] - d, HZ);                                 \
        if (t == 0) sk[9] = df; else sk[9-t] = sk[9-t] + df;            \
    }

#define RINGSHIFT()                                                     \
    {                                                                   \
        _Pragma("unroll")                                               \
        for (int j = 0; j < 9; ++j) sk[j] = sk[j + 1];                  \
    }

#define FINAL(wv)                                                       \
    {                                                                   \
        float c0v = (float)sk[0][0];                                    \
        float c1v = (float)sk[0][1];                                    \
        float cx = useX ? c0v : 0.f;                                    \
        float cy = useY ? c1v : 0.f;                                    \
        wsx += (wv).x * cx; wsy += (wv).y * cy;                         \
        rsx += cx;          rsy += cy;                                  \
    }

    // ---- warmup s in [0,14): FULL unroll -> gating folds, shifts rename ----
#pragma unroll
    for (int s = 0; s < 14; ++s) {
        const int f = r0 - 11 + s;
        CVTROW(f);
        PREFETCH(f + 1);
        h2 nr = nv;
#pragma unroll
        for (int t = 0; t < 6; ++t) {
            if (s >= 2 * t) ALEVEL(t);
        }
        W[6][0] = W[6][1]; W[6][1] = W[6][2]; W[6][2] = nr;
    }
    // ---- mid s in [14,23): FULL unroll -> B gate t<=s-14 is compile-time ----
#pragma unroll
    for (int s = 14; s < 23; ++s) {
        const int f = r0 - 11 + s;
        CVTROW(f);
        PREFETCH(f + 1);
        RINGSHIFT();
#pragma unroll
        for (int t = 0; t < 10; ++t) {
            if (t <= s - 14) BLEVEL(t, f);
        }
        h2 nr = nv;
#pragma unroll
        for (int t = 0; t < 10; ++t) ALEVEL(t);
        W[10][0] = W[10][1]; W[10][1] = W[10][2]; W[10][2] = nr;
    }
    // ---- steady s in [23,NSTEP-1): unroll x5 (15 iters = 3 x 5) ----
#pragma unroll 5
    for (int s = 23; s < NSTEP - 1; ++s) {
        const int f = r0 - 11 + s;
        CVTROW(f);
        if (s < NSTEP - 2) PREFETCH(f + 1);
        float2 wcur = wnext;
        wnext = *(const float2*)wp; wp += WW;
        RINGSHIFT();
#pragma unroll
        for (int t = 0; t < 10; ++t) BLEVEL(t, f);
        FINAL(wcur);
        h2 nr = nv;
#pragma unroll
        for (int t = 0; t < 10; ++t) ALEVEL(t);
        W[10][0] = W[10][1]; W[10][1] = W[10][2]; W[10][2] = nr;
    }
    // ---- tail s = NSTEP-1: B + finalize only ----
    {
        const int f = r0 - 11 + NSTEP - 1;
        RINGSHIFT();
#pragma unroll
        for (int t = 0; t < 10; ++t) BLEVEL(t, f);
        FINAL(wnext);
    }

#undef CVTROW
#undef PREFETCH
#undef ALEVEL
#undef BLEVEL
#undef RINGSHIFT
#undef FINAL

    // ---- deterministic wave reduction ----
    float pw = wsx + wsy;
    float pr = rsx + rsy;
#pragma unroll
    for (int off = 32; off; off >>= 1) {
        pw += __shfl_down(pw, off, 64);
        pr += __shfl_down(pr, off, 64);
    }
    if (lane == 0) { partials[2 * wid] = pw; partials[2 * wid + 1] = pr; }
}

// ---------------- bitwise path (chain 1: img=target binary, weight=sigmoid(pred))
// Unchanged from R5 (exact; small fraction of runtime).
__device__ void do_bits(const float* __restrict__ tgt, const float* __restrict__ prd,
                        int b, int u, int v, float* __restrict__ partials,
                        int wid, int lane)
{
    const int c = u * 40 - 12 + lane;
    const bool inImg = (c >= 0) && (c < WW);
    const int cc = min(max(c, 0), WW - 1);
    const size_t base = (size_t)b * HH * WW;
    const int w0 = 4 * v - 1;
    const int aL = ((lane + 63) & 63) << 2;
    const int aR = ((lane + 1) & 63) << 2;
    const bool vtop = (v == 0), vbot = (v == BSV - 1);

    unsigned w[6];
#pragma unroll
    for (int k = 0; k < 6; ++k) {
        const int gw = w0 + k;
        unsigned acc = 0xFFFFFFFFu;
        if (gw >= 0 && gw < 16) {
            acc = 0u;
            const float* rp = tgt + base + (size_t)(gw * 32) * WW + cc;
            for (int i = 0; i < 32; ++i) {
                acc |= ((__float_as_uint(*rp) >> 29) & 1u) << i;
                rp += WW;
            }
            acc = inImg ? acc : 0xFFFFFFFFu;
        }
        w[k] = acc;
    }

    unsigned P0[4] = {0,0,0,0}, P1[4] = {0,0,0,0}, P2[4] = {0,0,0,0}, P3[4] = {0,0,0,0};

#pragma unroll
    for (int t = 0; t < 10; ++t) {
        unsigned E[6];
#pragma unroll
        for (int k = 0; k < 6; ++k) {
            unsigned up = (w[k] << 1) | (k > 0 ? (w[k-1] >> 31) : 1u);
            unsigned dn = (w[k] >> 1) | (k < 5 ? (w[k+1] << 31) : 0x80000000u);
            unsigned vert = w[k] & up & dn;
            unsigned Lw = bpermu(aL, w[k]);
            unsigned Rw = bpermu(aR, w[k]);
            unsigned e = vert & Lw & Rw;
            E[k] = inImg ? e : 0xFFFFFFFFu;
        }
        if (vtop) E[0] = 0xFFFFFFFFu;
        if (vbot) E[5] = 0xFFFFFFFFu;

        const unsigned t0 = vtop ? 0u : E[0];
        const unsigned t5 = vbot ? 0u : E[5];
#pragma unroll
        for (int k = 1; k <= 4; ++k) {
            unsigned eu = (k == 1) ? t0 : E[k-1];
            unsigned ed = (k == 4) ? t5 : E[k+1];
            unsigned up = (E[k] << 1) | (eu >> 31);
            unsigned dn = (E[k] >> 1) | (ed << 31);
            unsigned V  = E[k] | up | dn;
            unsigned Vm = inImg ? V : 0u;
            unsigned D  = Vm | bpermu(aL, Vm) | bpermu(aR, Vm);
            unsigned contrib = w[k] & ~D;
            unsigned c0 = contrib & P0[k-1];  P0[k-1] ^= contrib;
            unsigned c1 = c0 & P1[k-1];       P1[k-1] ^= c0;
            unsigned c2 = c1 & P2[k-1];       P2[k-1] ^= c1;
            P3[k-1] ^= c2;
        }
#pragma unroll
        for (int k = 0; k < 6; ++k) w[k] = E[k];
    }

    const bool useful = inImg && (lane >= 12) && (lane < 52);
    unsigned rsum = 0;
#pragma unroll
    for (int k = 0; k < 4; ++k) {
        if (!useful) { P0[k] = 0; P1[k] = 0; P2[k] = 0; P3[k] = 0; }
        rsum += __popc(P0[k]) + 2*__popc(P1[k]) + 4*__popc(P2[k]) + 8*__popc(P3[k]);
    }
    float wsum = 0.f;
    const float* pp = prd + base + (size_t)(128 * v) * WW + cc;
    for (int i = 0; i < 32; ++i) {
#pragma unroll
        for (int k = 0; k < 4; ++k) {
            unsigned cnt = ((P0[k] >> i) & 1u) + (((P1[k] >> i) & 1u) << 1)
                         + (((P2[k] >> i) & 1u) << 2) + (((P3[k] >> i) & 1u) << 3);
            float p = sigf(pp[(size_t)(32 * k + i) * WW]);
            wsum += p * (float)cnt;
        }
    }

    float pw = wsum, pr = (float)rsum;
#pragma unroll
    for (int off = 32; off; off >>= 1) {
        pw += __shfl_down(pw, off, 64);
        pr += __shfl_down(pr, off, 64);
    }
    if (lane == 0) { partials[2 * wid] = pw; partials[2 * wid + 1] = pr; }
}

// 64-thread blocks (1 wave/block): float tasks = blocks 0..NF-1 -> exactly
// 10 float waves per CU under round-robin dispatch; bit tasks spread 3-4/CU.
__global__ __launch_bounds__(64)
void cld_main(const float* __restrict__ pred, const float* __restrict__ target,
              float* __restrict__ partials)
{
    const int wid  = blockIdx.x;
    const int lane = threadIdx.x;

    if (wid < NF) {
        // -------- float chain 0 (fp16x2 packed) --------
        int t_ = wid;
        const int b = t_ / (FSH * FSV);  t_ -= b * (FSH * FSV);
        const int u = t_ / FSV;
        const int v = t_ - u * FSV;
        const int r0 = v * RV;
        const int cbase = u * 102 - 12;
        const int UW = (u == FSH - 1) ? 104 : 102;

        const int c0 = cbase + 2 * lane;
        const int c1 = c0 + 1;
        const bool ok0 = (c0 >= 0) && (c0 < WW);
        const bool ok1 = (c1 >= 0) && (c1 < WW);
        const int wc0 = 2 * lane;
        const bool useX = (wc0     >= 12) && (wc0     < 12 + UW);
        const bool useY = (wc0 + 1 >= 12) && (wc0 + 1 < 12 + UW);
        // eclamp: ok -> -inf (no-op for hmax), OOB -> +inf (force erode pad)
        // dclamp: ok -> +inf (no-op for hmin), OOB -> -inf (force dilate pad)
        const unsigned elo = ok0 ? 0xFC00u : 0x7C00u;
        const unsigned ehi = ok1 ? 0xFC00u : 0x7C00u;
        const h2 eclamp = h2bits(elo | (ehi << 16));
        const h2 dclamp = h2bits((elo | (ehi << 16)) ^ 0x80008000u);
        const int cc = min(max(c0, 0), WW - 2);

        const float* ip = pred   + (size_t)b * HH * WW + (ptrdiff_t)(r0 - 11) * WW + cc;
        const float* wp = target + (size_t)b * HH * WW + (size_t)r0 * WW + cc;

        if (v == 0 || v == FSV - 1)
            do_strip<true >(ip, wp, r0, ok0, ok1, useX, useY, eclamp, dclamp, partials, wid, lane);
        else
            do_strip<false>(ip, wp, r0, ok0, ok1, useX, useY, eclamp, dclamp, partials, wid, lane);
    } else {
        // -------- bitwise chain 1 --------
        int idx = wid - NF;
        const int b = idx / (BSU * BSV);  idx -= b * (BSU * BSV);
        const int u = idx / BSV;
        const int v = idx - u * BSV;
        do_bits(target, pred, b, u, v, partials, wid, lane);
    }
}

// Deterministic final reduction + loss formula.
__global__ void cld_final(const float* __restrict__ partials, float* __restrict__ out)
{
    const int tid = threadIdx.x;
    double a0 = 0, a1 = 0, a2 = 0, a3 = 0;
    for (int i = tid; i < NF; i += 256) {
        a0 += (double)partials[2 * i];          // sum(target*skel_pred)
        a1 += (double)partials[2 * i + 1];      // sum(skel_pred)
    }
    for (int i = NF + tid; i < NTASK; i += 256) {
        a2 += (double)partials[2 * i];          // sum(p*skel_gt)
        a3 += (double)partials[2 * i + 1];      // sum(skel_gt)
    }
    __shared__ double red[256][4];
    red[tid][0] = a0; red[tid][1] = a1; red[tid][2] = a2; red[tid][3] = a3;
    __syncthreads();
    for (int s2 = 128; s2 > 0; s2 >>= 1) {
        if (tid < s2) {
            red[tid][0] += red[tid + s2][0]; red[tid][1] += red[tid + s2][1];
            red[tid][2] += red[tid + s2][2]; red[tid][3] += red[tid + s2][3];
        }
        __syncthreads();
    }
    if (tid == 0) {
        double tsens = red[0][0] / (red[0][1] + 1e-6);
        double tprec = red[0][2] / (red[0][3] + 1e-6);
        double cl = 2.0 * tprec * tsens / (tprec + tsens + 1e-6);
        out[0] = (float)(1.0 - cl);
    }
}

extern "C" void kernel_launch(void* const* d_in, const int* in_sizes, int n_in,
                              void* d_out, int out_size, void* d_ws, size_t ws_size,
                              hipStream_t stream) {
    const float* pred   = (const float*)d_in[0];
    const float* target = (const float*)d_in[1];
    float* out = (float*)d_out;
    float* partials = (float*)d_ws;            // NTASK*2 floats = ~27 KB

    hipLaunchKernelGGL(cld_main, dim3(NTASK), dim3(64), 0, stream,
                       pred, target, partials);
    hipLaunchKernelGGL(cld_final, dim3(1), dim3(256), 0, stream, partials, out);
}

// Round 14
// 74.462 us; speedup vs baseline: 1.2808x; 1.2808x over previous
//
#include <hip/hip_runtime.h>
#include <math.h>

// Problem constants (fixed by reference setup_inputs)
#define HH 512
#define WW 512
#define NBATCH 16
#define RV 16                      // float path: output rows per strip
#define FSV (HH/RV)                // 32
#define FSH 5                      // float path: horizontal strips (stride 102)
#define NF (NBATCH*FSH*FSV)        // 2560 float wave tasks (= exactly 10/CU)
#define BSU 13                     // bit path: col strips (64 wide, 40 useful)
#define BSV 4                      // bit path: row bands (128 useful rows)
#define NBT (NBATCH*BSU*BSV)       // 832 bitwise wave tasks (chain 1)
#define NTASK (NF + NBT)           // 3392
#define NSTEP (RV + 23)            // 39 steps per strip
#define FINF  (__builtin_huge_valf())

typedef _Float16 h2 __attribute__((ext_vector_type(2)));

__device__ __forceinline__ float sigf(float x) { return 1.0f / (1.0f + __expf(-x)); }
__device__ __forceinline__ unsigned bpermu(int a, unsigned v) {
    return (unsigned)__builtin_amdgcn_ds_bpermute(a, (int)v);
}
__device__ __forceinline__ h2 h2bits(unsigned u) { return __builtin_bit_cast(h2, u); }
__device__ __forceinline__ unsigned bitsh2(h2 h) { return __builtin_bit_cast(unsigned, h); }
__device__ __forceinline__ h2 hmin2(h2 a, h2 b) { return __builtin_elementwise_min(a, b); }
__device__ __forceinline__ h2 hmax2(h2 a, h2 b) { return __builtin_elementwise_max(a, b); }
// DPP wave shifts (VALU, no LDS pipe); boundary lanes keep own value —
// garbage confined to 12-col strip halo (<=11-col propagation).
__device__ __forceinline__ h2 dpp_prev(h2 v) {
    unsigned u = bitsh2(v);
    return h2bits((unsigned)__builtin_amdgcn_update_dpp((int)u, (int)u, 0x130, 0xF, 0xF, false));
}
__device__ __forceinline__ h2 dpp_next(h2 v) {
    unsigned u = bitsh2(v);
    return h2bits((unsigned)__builtin_amdgcn_update_dpp((int)u, (int)u, 0x138, 0xF, 0xF, false));
}
// Packed col-shift vectors (single v_alignbit_b32 where available).
#if __has_builtin(__builtin_amdgcn_alignbit)
__device__ __forceinline__ h2 lvec2(h2 prev, h2 self) {
    return h2bits(__builtin_amdgcn_alignbit(bitsh2(self), bitsh2(prev), 16));
}
__device__ __forceinline__ h2 rvec2(h2 self, h2 next) {
    return h2bits(__builtin_amdgcn_alignbit(bitsh2(next), bitsh2(self), 16));
}
#else
__device__ __forceinline__ h2 lvec2(h2 prev, h2 self) {
    return h2bits((bitsh2(prev) >> 16) | (bitsh2(self) << 16));
}
__device__ __forceinline__ h2 rvec2(h2 self, h2 next) {
    return h2bits((bitsh2(self) >> 16) | (bitsh2(next) << 16));
}
#endif

// ---------------- float path (chain 0: img=sigmoid(pred), weight=target) ----
// fp16x2-packed morphology; warmup/mid gating proved exact (absmax=0 chain).
// R14 = R12 base (VGPR 68, 73.6us) + unroll x3 on the STEADY loop only.
// R13's full warmup/mid unroll blew VGPR to 140 (occupancy 8%) — cold phases
// must stay rolled; only the hot 15-iter steady loop gets SSA renaming of
// the ring/window shifts.
template<bool GUARD>
__device__ __forceinline__ void do_strip(
    const float* __restrict__ ip, const float* __restrict__ wp,
    int r0, bool ok0, bool ok1, bool useX, bool useY,
    h2 eclamp, h2 dclamp,
    float* __restrict__ partials, int wid, int lane)
{
    const h2 HP = h2bits(0x7C007C00u);   // +inf pair
    const h2 HN = h2bits(0xFC00FC00u);   // -inf pair
    const h2 HZ = h2bits(0u);

    h2 W[11][3], sk[10];
#pragma unroll
    for (int t = 0; t < 11; ++t) { W[t][0] = HP; W[t][1] = HP; W[t][2] = HP; }
#pragma unroll
    for (int j = 0; j < 10; ++j) sk[j] = HZ;
    float wsx = 0.f, wsy = 0.f, rsx = 0.f, rsy = 0.f;

    // ---- prefetch prologue: img row r0-11, weight row r0 ----
    float2 raw;
    if (!GUARD || (unsigned)(r0 - 11) < (unsigned)HH) raw = *(const float2*)ip;
    ip += WW;
    float2 wnext = *(const float2*)wp;   // weight rows r0..r0+RV-1 always valid
    wp += WW;

// convert last step's prefetched row (row fv)
#define CVTROW(fv)                                                      \
    h2 nv;                                                              \
    {                                                                   \
        if (!GUARD || (unsigned)(fv) < (unsigned)HH) {                  \
            float x = sigf(raw.x); x = ok0 ? x : FINF;                  \
            float y = sigf(raw.y); y = ok1 ? y : FINF;                  \
            nv[0] = (_Float16)x; nv[1] = (_Float16)y;                   \
        } else nv = HP;                                                 \
    }

#define PREFETCH(fnext)                                                 \
    {                                                                   \
        if (!GUARD || (unsigned)(fnext) < (unsigned)HH)                 \
            raw = *(const float2*)ip;                                   \
        ip += WW;                                                       \
    }

#define ALEVEL(t)                                                       \
    {                                                                   \
        W[t][0] = W[t][1]; W[t][1] = W[t][2]; W[t][2] = nr;             \
        h2 a0 = W[t][0], a1 = W[t][1], a2 = W[t][2];                    \
        h2 vmin = hmin2(hmin2(a0, a1), a2);                             \
        h2 pv = dpp_prev(a1), nx = dpp_next(a1);                        \
        h2 lv = lvec2(pv, a1), rv = rvec2(a1, nx);                      \
        h2 e = hmin2(vmin, hmin2(lv, rv));                              \
        nr = hmax2(e, eclamp);                                          \
    }

#define BLEVEL(t, fv)                                                   \
    {                                                                   \
        h2 b0 = W[t+1][0], b1 = W[t+1][1], b2 = W[t+1][2];              \
        if (GUARD) {                                                    \
            if ((unsigned)((fv) - t - 4) >= (unsigned)HH) b0 = HN;      \
            if ((unsigned)((fv) - t - 3) >= (unsigned)HH) b1 = HN;      \
            if ((unsigned)((fv) - t - 2) >= (unsigned)HH) b2 = HN;      \
        }                                                               \
        h2 cm = hmin2(hmax2(hmax2(b0, b1), b2), dclamp);                \
        h2 pv = dpp_prev(cm), nx = dpp_next(cm);                        \
        h2 lv = lvec2(pv, cm), rv = rvec2(cm, nx);                      \
        h2 d = hmax2(cm, hmax2(lv, rv));                                \
        h2 df = hmax2(W[t][0] - d, HZ);                                 \
        if (t == 0) sk[9] = df; else sk[9-t] = sk[9-t] + df;            \
    }

#define RINGSHIFT()                                                     \
    {                                                                   \
        _Pragma("unroll")                                               \
        for (int j = 0; j < 9; ++j) sk[j] = sk[j + 1];                  \
    }

#define FINAL(wv)                                                       \
    {                                                                   \
        float c0v = (float)sk[0][0];                                    \
        float c1v = (float)sk[0][1];                                    \
        float cx = useX ? c0v : 0.f;                                    \
        float cy = useY ? c1v : 0.f;                                    \
        wsx += (wv).x * cx; wsy += (wv).y * cy;                         \
        rsx += cx;          rsy += cy;                                  \
    }

    // ---- warmup s in [0,14): rolled (cold; R13 showed unroll here = VGPR) ----
    for (int s = 0; s < 14; ++s) {
        const int f = r0 - 11 + s;
        CVTROW(f);
        PREFETCH(f + 1);
        h2 nr = nv;
#pragma unroll
        for (int t = 0; t < 6; ++t) {
            if (s >= 2 * t) ALEVEL(t);
        }
        W[6][0] = W[6][1]; W[6][1] = W[6][2]; W[6][2] = nr;
    }
    // ---- mid s in [14,23): rolled, B gated to t <= s-14, full A ----
    for (int s = 14; s < 23; ++s) {
        const int f = r0 - 11 + s;
        CVTROW(f);
        PREFETCH(f + 1);
        RINGSHIFT();
#pragma unroll
        for (int t = 0; t < 10; ++t) {
            if (t <= s - 14) BLEVEL(t, f);
        }
        h2 nr = nv;
#pragma unroll
        for (int t = 0; t < 10; ++t) ALEVEL(t);
        W[10][0] = W[10][1]; W[10][1] = W[10][2]; W[10][2] = nr;
    }
    // ---- steady s in [23,NSTEP-1): HOT — unroll x3 renames ring/window shifts
#pragma unroll 3
    for (int s = 23; s < NSTEP - 1; ++s) {
        const int f = r0 - 11 + s;
        CVTROW(f);
        if (s < NSTEP - 2) PREFETCH(f + 1);
        float2 wcur = wnext;
        wnext = *(const float2*)wp; wp += WW;
        RINGSHIFT();
#pragma unroll
        for (int t = 0; t < 10; ++t) BLEVEL(t, f);
        FINAL(wcur);
        h2 nr = nv;
#pragma unroll
        for (int t = 0; t < 10; ++t) ALEVEL(t);
        W[10][0] = W[10][1]; W[10][1] = W[10][2]; W[10][2] = nr;
    }
    // ---- tail s = NSTEP-1: B + finalize only ----
    {
        const int f = r0 - 11 + NSTEP - 1;
        RINGSHIFT();
#pragma unroll
        for (int t = 0; t < 10; ++t) BLEVEL(t, f);
        FINAL(wnext);
    }

#undef CVTROW
#undef PREFETCH
#undef ALEVEL
#undef BLEVEL
#undef RINGSHIFT
#undef FINAL

    // ---- deterministic wave reduction ----
    float pw = wsx + wsy;
    float pr = rsx + rsy;
#pragma unroll
    for (int off = 32; off; off >>= 1) {
        pw += __shfl_down(pw, off, 64);
        pr += __shfl_down(pr, off, 64);
    }
    if (lane == 0) { partials[2 * wid] = pw; partials[2 * wid + 1] = pr; }
}

// ---------------- bitwise path (chain 1: img=target binary, weight=sigmoid(pred))
// Unchanged from R5 (exact; small fraction of runtime).
__device__ void do_bits(const float* __restrict__ tgt, const float* __restrict__ prd,
                        int b, int u, int v, float* __restrict__ partials,
                        int wid, int lane)
{
    const int c = u * 40 - 12 + lane;
    const bool inImg = (c >= 0) && (c < WW);
    const int cc = min(max(c, 0), WW - 1);
    const size_t base = (size_t)b * HH * WW;
    const int w0 = 4 * v - 1;
    const int aL = ((lane + 63) & 63) << 2;
    const int aR = ((lane + 1) & 63) << 2;
    const bool vtop = (v == 0), vbot = (v == BSV - 1);

    unsigned w[6];
#pragma unroll
    for (int k = 0; k < 6; ++k) {
        const int gw = w0 + k;
        unsigned acc = 0xFFFFFFFFu;
        if (gw >= 0 && gw < 16) {
            acc = 0u;
            const float* rp = tgt + base + (size_t)(gw * 32) * WW + cc;
            for (int i = 0; i < 32; ++i) {
                acc |= ((__float_as_uint(*rp) >> 29) & 1u) << i;
                rp += WW;
            }
            acc = inImg ? acc : 0xFFFFFFFFu;
        }
        w[k] = acc;
    }

    unsigned P0[4] = {0,0,0,0}, P1[4] = {0,0,0,0}, P2[4] = {0,0,0,0}, P3[4] = {0,0,0,0};

#pragma unroll
    for (int t = 0; t < 10; ++t) {
        unsigned E[6];
#pragma unroll
        for (int k = 0; k < 6; ++k) {
            unsigned up = (w[k] << 1) | (k > 0 ? (w[k-1] >> 31) : 1u);
            unsigned dn = (w[k] >> 1) | (k < 5 ? (w[k+1] << 31) : 0x80000000u);
            unsigned vert = w[k] & up & dn;
            unsigned Lw = bpermu(aL, w[k]);
            unsigned Rw = bpermu(aR, w[k]);
            unsigned e = vert & Lw & Rw;
            E[k] = inImg ? e : 0xFFFFFFFFu;
        }
        if (vtop) E[0] = 0xFFFFFFFFu;
        if (vbot) E[5] = 0xFFFFFFFFu;

        const unsigned t0 = vtop ? 0u : E[0];
        const unsigned t5 = vbot ? 0u : E[5];
#pragma unroll
        for (int k = 1; k <= 4; ++k) {
            unsigned eu = (k == 1) ? t0 : E[k-1];
            unsigned ed = (k == 4) ? t5 : E[k+1];
            unsigned up = (E[k] << 1) | (eu >> 31);
            unsigned dn = (E[k] >> 1) | (ed << 31);
            unsigned V  = E[k] | up | dn;
            unsigned Vm = inImg ? V : 0u;
            unsigned D  = Vm | bpermu(aL, Vm) | bpermu(aR, Vm);
            unsigned contrib = w[k] & ~D;
            unsigned c0 = contrib & P0[k-1];  P0[k-1] ^= contrib;
            unsigned c1 = c0 & P1[k-1];       P1[k-1] ^= c0;
            unsigned c2 = c1 & P2[k-1];       P2[k-1] ^= c1;
            P3[k-1] ^= c2;
        }
#pragma unroll
        for (int k = 0; k < 6; ++k) w[k] = E[k];
    }

    const bool useful = inImg && (lane >= 12) && (lane < 52);
    unsigned rsum = 0;
#pragma unroll
    for (int k = 0; k < 4; ++k) {
        if (!useful) { P0[k] = 0; P1[k] = 0; P2[k] = 0; P3[k] = 0; }
        rsum += __popc(P0[k]) + 2*__popc(P1[k]) + 4*__popc(P2[k]) + 8*__popc(P3[k]);
    }
    float wsum = 0.f;
    const float* pp = prd + base + (size_t)(128 * v) * WW + cc;
    for (int i = 0; i < 32; ++i) {
#pragma unroll
        for (int k = 0; k < 4; ++k) {
            unsigned cnt = ((P0[k] >> i) & 1u) + (((P1[k] >> i) & 1u) << 1)
                         + (((P2[k] >> i) & 1u) << 2) + (((P3[k] >> i) & 1u) << 3);
            float p = sigf(pp[(size_t)(32 * k + i) * WW]);
            wsum += p * (float)cnt;
        }
    }

    float pw = wsum, pr = (float)rsum;
#pragma unroll
    for (int off = 32; off; off >>= 1) {
        pw += __shfl_down(pw, off, 64);
        pr += __shfl_down(pr, off, 64);
    }
    if (lane == 0) { partials[2 * wid] = pw; partials[2 * wid + 1] = pr; }
}

// 64-thread blocks (1 wave/block): float tasks = blocks 0..NF-1 -> exactly
// 10 float waves per CU under round-robin dispatch; bit tasks spread 3-4/CU.
__global__ __launch_bounds__(64)
void cld_main(const float* __restrict__ pred, const float* __restrict__ target,
              float* __restrict__ partials)
{
    const int wid  = blockIdx.x;
    const int lane = threadIdx.x;

    if (wid < NF) {
        // -------- float chain 0 (fp16x2 packed) --------
        int t_ = wid;
        const int b = t_ / (FSH * FSV);  t_ -= b * (FSH * FSV);
        const int u = t_ / FSV;
        const int v = t_ - u * FSV;
        const int r0 = v * RV;
        const int cbase = u * 102 - 12;
        const int UW = (u == FSH - 1) ? 104 : 102;

        const int c0 = cbase + 2 * lane;
        const int c1 = c0 + 1;
        const bool ok0 = (c0 >= 0) && (c0 < WW);
        const bool ok1 = (c1 >= 0) && (c1 < WW);
        const int wc0 = 2 * lane;
        const bool useX = (wc0     >= 12) && (wc0     < 12 + UW);
        const bool useY = (wc0 + 1 >= 12) && (wc0 + 1 < 12 + UW);
        // eclamp: ok -> -inf (no-op for hmax), OOB -> +inf (force erode pad)
        // dclamp: ok -> +inf (no-op for hmin), OOB -> -inf (force dilate pad)
        const unsigned elo = ok0 ? 0xFC00u : 0x7C00u;
        const unsigned ehi = ok1 ? 0xFC00u : 0x7C00u;
        const h2 eclamp = h2bits(elo | (ehi << 16));
        const h2 dclamp = h2bits((elo | (ehi << 16)) ^ 0x80008000u);
        const int cc = min(max(c0, 0), WW - 2);

        const float* ip = pred   + (size_t)b * HH * WW + (ptrdiff_t)(r0 - 11) * WW + cc;
        const float* wp = target + (size_t)b * HH * WW + (size_t)r0 * WW + cc;

        if (v == 0 || v == FSV - 1)
            do_strip<true >(ip, wp, r0, ok0, ok1, useX, useY, eclamp, dclamp, partials, wid, lane);
        else
            do_strip<false>(ip, wp, r0, ok0, ok1, useX, useY, eclamp, dclamp, partials, wid, lane);
    } else {
        // -------- bitwise chain 1 --------
        int idx = wid - NF;
        const int b = idx / (BSU * BSV);  idx -= b * (BSU * BSV);
        const int u = idx / BSV;
        const int v = idx - u * BSV;
        do_bits(target, pred, b, u, v, partials, wid, lane);
    }
}

// Deterministic final reduction + loss formula.
__global__ void cld_final(const float* __restrict__ partials, float* __restrict__ out)
{
    const int tid = threadIdx.x;
    double a0 = 0, a1 = 0, a2 = 0, a3 = 0;
    for (int i = tid; i < NF; i += 256) {
        a0 += (double)partials[2 * i];          // sum(target*skel_pred)
        a1 += (double)partials[2 * i + 1];      // sum(skel_pred)
    }
    for (int i = NF + tid; i < NTASK; i += 256) {
        a2 += (double)partials[2 * i];          // sum(p*skel_gt)
        a3 += (double)partials[2 * i + 1];      // sum(skel_gt)
    }
    __shared__ double red[256][4];
    red[tid][0] = a0; red[tid][1] = a1; red[tid][2] = a2; red[tid][3] = a3;
    __syncthreads();
    for (int s2 = 128; s2 > 0; s2 >>= 1) {
        if (tid < s2) {
            red[tid][0] += red[tid + s2][0]; red[tid][1] += red[tid + s2][1];
            red[tid][2] += red[tid + s2][2]; red[tid][3] += red[tid + s2][3];
        }
        __syncthreads();
    }
    if (tid == 0) {
        double tsens = red[0][0] / (red[0][1] + 1e-6);
        double tprec = red[0][2] / (red[0][3] + 1e-6);
        double cl = 2.0 * tprec * tsens / (tprec + tsens + 1e-6);
        out[0] = (float)(1.0 - cl);
    }
}

extern "C" void kernel_launch(void* const* d_in, const int* in_sizes, int n_in,
                              void* d_out, int out_size, void* d_ws, size_t ws_size,
                              hipStream_t stream) {
    const float* pred   = (const float*)d_in[0];
    const float* target = (const float*)d_in[1];
    float* out = (float*)d_out;
    float* partials = (float*)d_ws;            // NTASK*2 floats = ~27 KB

    hipLaunchKernelGGL(cld_main, dim3(NTASK), dim3(64), 0, stream,
                       pred, target, partials);
    hipLaunchKernelGGL(cld_final, dim3(1), dim3(256), 0, stream, partials, out);
}

// Round 15
// 73.471 us; speedup vs baseline: 1.2981x; 1.0135x over previous
//
#include <hip/hip_runtime.h>
#include <math.h>

// Problem constants (fixed by reference setup_inputs)
#define HH 512
#define WW 512
#define NBATCH 16
#define RV 16                      // float path: output rows per strip
#define FSV (HH/RV)                // 32
#define FSH 5                      // float path: horizontal strips (stride 102)
#define NF (NBATCH*FSH*FSV)        // 2560 float wave tasks (= exactly 10/CU)
#define BSU 13                     // bit path: col strips (64 wide, 40 useful)
#define BSV 4                      // bit path: row bands (128 useful rows)
#define NBT (NBATCH*BSU*BSV)       // 832 bitwise wave tasks (chain 1)
#define NTASK (NF + NBT)           // 3392
#define NSTEP (RV + 23)            // 39 steps per strip
#define FINF  (__builtin_huge_valf())

typedef _Float16 h2 __attribute__((ext_vector_type(2)));

__device__ __forceinline__ float sigf(float x) { return 1.0f / (1.0f + __expf(-x)); }
__device__ __forceinline__ unsigned bpermu(int a, unsigned v) {
    return (unsigned)__builtin_amdgcn_ds_bpermute(a, (int)v);
}
__device__ __forceinline__ h2 h2bits(unsigned u) { return __builtin_bit_cast(h2, u); }
__device__ __forceinline__ unsigned bitsh2(h2 h) { return __builtin_bit_cast(unsigned, h); }
__device__ __forceinline__ h2 hmin2(h2 a, h2 b) { return __builtin_elementwise_min(a, b); }
__device__ __forceinline__ h2 hmax2(h2 a, h2 b) { return __builtin_elementwise_max(a, b); }
// DPP wave shifts (VALU, no LDS pipe); boundary lanes keep own value —
// garbage confined to 12-col strip halo (<=11-col propagation).
__device__ __forceinline__ h2 dpp_prev(h2 v) {
    unsigned u = bitsh2(v);
    return h2bits((unsigned)__builtin_amdgcn_update_dpp((int)u, (int)u, 0x130, 0xF, 0xF, false));
}
__device__ __forceinline__ h2 dpp_next(h2 v) {
    unsigned u = bitsh2(v);
    return h2bits((unsigned)__builtin_amdgcn_update_dpp((int)u, (int)u, 0x138, 0xF, 0xF, false));
}
// Packed col-shift vectors (single v_alignbit_b32 where available).
#if __has_builtin(__builtin_amdgcn_alignbit)
__device__ __forceinline__ h2 lvec2(h2 prev, h2 self) {
    return h2bits(__builtin_amdgcn_alignbit(bitsh2(self), bitsh2(prev), 16));
}
__device__ __forceinline__ h2 rvec2(h2 self, h2 next) {
    return h2bits(__builtin_amdgcn_alignbit(bitsh2(next), bitsh2(self), 16));
}
#else
__device__ __forceinline__ h2 lvec2(h2 prev, h2 self) {
    return h2bits((bitsh2(prev) >> 16) | (bitsh2(self) << 16));
}
__device__ __forceinline__ h2 rvec2(h2 self, h2 next) {
    return h2bits((bitsh2(self) >> 16) | (bitsh2(next) << 16));
}
#endif

// ---------------- float path (chain 0: img=sigmoid(pred), weight=target) ----
// fp16x2-packed morphology; warmup/mid gating proved exact (absmax=0 chain).
// Software prefetch: img row and weight row loaded one step ahead.
// RV=16 -> 10 float waves/CU. Final configuration (best of R0-R14 sweep):
//  - instr packing (fp16/DPP/alignbit), exact warmup/mid/tail gating,
//    wave-granular dispatch, prefetch. Unrolling (R13/R14) regresses via
//    VGPR/occupancy; RV=32 (R11) starves TLP; structure plateaus ~73.6us.
template<bool GUARD>
__device__ __forceinline__ void do_strip(
    const float* __restrict__ ip, const float* __restrict__ wp,
    int r0, bool ok0, bool ok1, bool useX, bool useY,
    h2 eclamp, h2 dclamp,
    float* __restrict__ partials, int wid, int lane)
{
    const h2 HP = h2bits(0x7C007C00u);   // +inf pair
    const h2 HN = h2bits(0xFC00FC00u);   // -inf pair
    const h2 HZ = h2bits(0u);

    h2 W[11][3], sk[10];
#pragma unroll
    for (int t = 0; t < 11; ++t) { W[t][0] = HP; W[t][1] = HP; W[t][2] = HP; }
#pragma unroll
    for (int j = 0; j < 10; ++j) sk[j] = HZ;
    float wsx = 0.f, wsy = 0.f, rsx = 0.f, rsy = 0.f;

    // ---- prefetch prologue: img row r0-11, weight row r0 ----
    float2 raw;
    if (!GUARD || (unsigned)(r0 - 11) < (unsigned)HH) raw = *(const float2*)ip;
    ip += WW;
    float2 wnext = *(const float2*)wp;   // weight rows r0..r0+RV-1 always valid
    wp += WW;

// convert last step's prefetched row (row fv)
#define CVTROW(fv)                                                      \
    h2 nv;                                                              \
    {                                                                   \
        if (!GUARD || (unsigned)(fv) < (unsigned)HH) {                  \
            float x = sigf(raw.x); x = ok0 ? x : FINF;                  \
            float y = sigf(raw.y); y = ok1 ? y : FINF;                  \
            nv[0] = (_Float16)x; nv[1] = (_Float16)y;                   \
        } else nv = HP;                                                 \
    }

#define PREFETCH(fnext)                                                 \
    {                                                                   \
        if (!GUARD || (unsigned)(fnext) < (unsigned)HH)                 \
            raw = *(const float2*)ip;                                   \
        ip += WW;                                                       \
    }

#define ALEVEL(t)                                                       \
    {                                                                   \
        W[t][0] = W[t][1]; W[t][1] = W[t][2]; W[t][2] = nr;             \
        h2 a0 = W[t][0], a1 = W[t][1], a2 = W[t][2];                    \
        h2 vmin = hmin2(hmin2(a0, a1), a2);                             \
        h2 pv = dpp_prev(a1), nx = dpp_next(a1);                        \
        h2 lv = lvec2(pv, a1), rv = rvec2(a1, nx);                      \
        h2 e = hmin2(vmin, hmin2(lv, rv));                              \
        nr = hmax2(e, eclamp);                                          \
    }

#define BLEVEL(t, fv)                                                   \
    {                                                                   \
        h2 b0 = W[t+1][0], b1 = W[t+1][1], b2 = W[t+1][2];              \
        if (GUARD) {                                                    \
            if ((unsigned)((fv) - t - 4) >= (unsigned)HH) b0 = HN;      \
            if ((unsigned)((fv) - t - 3) >= (unsigned)HH) b1 = HN;      \
            if ((unsigned)((fv) - t - 2) >= (unsigned)HH) b2 = HN;      \
        }                                                               \
        h2 cm = hmin2(hmax2(hmax2(b0, b1), b2), dclamp);                \
        h2 pv = dpp_prev(cm), nx = dpp_next(cm);                        \
        h2 lv = lvec2(pv, cm), rv = rvec2(cm, nx);                      \
        h2 d = hmax2(cm, hmax2(lv, rv));                                \
        h2 df = hmax2(W[t][0] - d, HZ);                                 \
        if (t == 0) sk[9] = df; else sk[9-t] = sk[9-t] + df;            \
    }

#define RINGSHIFT()                                                     \
    {                                                                   \
        _Pragma("unroll")                                               \
        for (int j = 0; j < 9; ++j) sk[j] = sk[j + 1];                  \
    }

#define FINAL(wv)                                                       \
    {                                                                   \
        float c0v = (float)sk[0][0];                                    \
        float c1v = (float)sk[0][1];                                    \
        float cx = useX ? c0v : 0.f;                                    \
        float cy = useY ? c1v : 0.f;                                    \
        wsx += (wv).x * cx; wsy += (wv).y * cy;                         \
        rsx += cx;          rsy += cy;                                  \
    }

    // ---- warmup s in [0,14): cvt+prefetch + A levels (level t from s=2t) ----
    for (int s = 0; s < 14; ++s) {
        const int f = r0 - 11 + s;
        CVTROW(f);
        PREFETCH(f + 1);
        h2 nr = nv;
#pragma unroll
        for (int t = 0; t < 6; ++t) {
            if (s >= 2 * t) ALEVEL(t);
        }
        W[6][0] = W[6][1]; W[6][1] = W[6][2]; W[6][2] = nr;
    }
    // ---- mid s in [14,23): B gated to t <= s-14, full A ----
    for (int s = 14; s < 23; ++s) {
        const int f = r0 - 11 + s;
        CVTROW(f);
        PREFETCH(f + 1);
        RINGSHIFT();
#pragma unroll
        for (int t = 0; t < 10; ++t) {
            if (t <= s - 14) BLEVEL(t, f);
        }
        h2 nr = nv;
#pragma unroll
        for (int t = 0; t < 10; ++t) ALEVEL(t);
        W[10][0] = W[10][1]; W[10][1] = W[10][2]; W[10][2] = nr;
    }
    // ---- steady s in [23,NSTEP-1): full B + finalize + full A ----
    for (int s = 23; s < NSTEP - 1; ++s) {
        const int f = r0 - 11 + s;
        CVTROW(f);
        if (s < NSTEP - 2) PREFETCH(f + 1);
        float2 wcur = wnext;
        wnext = *(const float2*)wp; wp += WW;
        RINGSHIFT();
#pragma unroll
        for (int t = 0; t < 10; ++t) BLEVEL(t, f);
        FINAL(wcur);
        h2 nr = nv;
#pragma unroll
        for (int t = 0; t < 10; ++t) ALEVEL(t);
        W[10][0] = W[10][1]; W[10][1] = W[10][2]; W[10][2] = nr;
    }
    // ---- tail s = NSTEP-1: B + finalize only ----
    {
        const int f = r0 - 11 + NSTEP - 1;
        RINGSHIFT();
#pragma unroll
        for (int t = 0; t < 10; ++t) BLEVEL(t, f);
        FINAL(wnext);
    }

#undef CVTROW
#undef PREFETCH
#undef ALEVEL
#undef BLEVEL
#undef RINGSHIFT
#undef FINAL

    // ---- deterministic wave reduction ----
    float pw = wsx + wsy;
    float pr = rsx + rsy;
#pragma unroll
    for (int off = 32; off; off >>= 1) {
        pw += __shfl_down(pw, off, 64);
        pr += __shfl_down(pr, off, 64);
    }
    if (lane == 0) { partials[2 * wid] = pw; partials[2 * wid + 1] = pr; }
}

// ---------------- bitwise path (chain 1: img=target binary, weight=sigmoid(pred))
// Exact integer morphology: 32 rows/u32, erode=AND(+inf pad->1), dilate=OR
// (pad->0), skel counts in 4 carry-save bitplanes.
__device__ void do_bits(const float* __restrict__ tgt, const float* __restrict__ prd,
                        int b, int u, int v, float* __restrict__ partials,
                        int wid, int lane)
{
    const int c = u * 40 - 12 + lane;
    const bool inImg = (c >= 0) && (c < WW);
    const int cc = min(max(c, 0), WW - 1);
    const size_t base = (size_t)b * HH * WW;
    const int w0 = 4 * v - 1;
    const int aL = ((lane + 63) & 63) << 2;
    const int aR = ((lane + 1) & 63) << 2;
    const bool vtop = (v == 0), vbot = (v == BSV - 1);

    unsigned w[6];
#pragma unroll
    for (int k = 0; k < 6; ++k) {
        const int gw = w0 + k;
        unsigned acc = 0xFFFFFFFFu;
        if (gw >= 0 && gw < 16) {
            acc = 0u;
            const float* rp = tgt + base + (size_t)(gw * 32) * WW + cc;
            for (int i = 0; i < 32; ++i) {
                acc |= ((__float_as_uint(*rp) >> 29) & 1u) << i;
                rp += WW;
            }
            acc = inImg ? acc : 0xFFFFFFFFu;
        }
        w[k] = acc;
    }

    unsigned P0[4] = {0,0,0,0}, P1[4] = {0,0,0,0}, P2[4] = {0,0,0,0}, P3[4] = {0,0,0,0};

#pragma unroll
    for (int t = 0; t < 10; ++t) {
        unsigned E[6];
#pragma unroll
        for (int k = 0; k < 6; ++k) {
            unsigned up = (w[k] << 1) | (k > 0 ? (w[k-1] >> 31) : 1u);
            unsigned dn = (w[k] >> 1) | (k < 5 ? (w[k+1] << 31) : 0x80000000u);
            unsigned vert = w[k] & up & dn;
            unsigned Lw = bpermu(aL, w[k]);
            unsigned Rw = bpermu(aR, w[k]);
            unsigned e = vert & Lw & Rw;
            E[k] = inImg ? e : 0xFFFFFFFFu;
        }
        if (vtop) E[0] = 0xFFFFFFFFu;
        if (vbot) E[5] = 0xFFFFFFFFu;

        const unsigned t0 = vtop ? 0u : E[0];
        const unsigned t5 = vbot ? 0u : E[5];
#pragma unroll
        for (int k = 1; k <= 4; ++k) {
            unsigned eu = (k == 1) ? t0 : E[k-1];
            unsigned ed = (k == 4) ? t5 : E[k+1];
            unsigned up = (E[k] << 1) | (eu >> 31);
            unsigned dn = (E[k] >> 1) | (ed << 31);
            unsigned V  = E[k] | up | dn;
            unsigned Vm = inImg ? V : 0u;
            unsigned D  = Vm | bpermu(aL, Vm) | bpermu(aR, Vm);
            unsigned contrib = w[k] & ~D;
            unsigned c0 = contrib & P0[k-1];  P0[k-1] ^= contrib;
            unsigned c1 = c0 & P1[k-1];       P1[k-1] ^= c0;
            unsigned c2 = c1 & P2[k-1];       P2[k-1] ^= c1;
            P3[k-1] ^= c2;
        }
#pragma unroll
        for (int k = 0; k < 6; ++k) w[k] = E[k];
    }

    const bool useful = inImg && (lane >= 12) && (lane < 52);
    unsigned rsum = 0;
#pragma unroll
    for (int k = 0; k < 4; ++k) {
        if (!useful) { P0[k] = 0; P1[k] = 0; P2[k] = 0; P3[k] = 0; }
        rsum += __popc(P0[k]) + 2*__popc(P1[k]) + 4*__popc(P2[k]) + 8*__popc(P3[k]);
    }
    float wsum = 0.f;
    const float* pp = prd + base + (size_t)(128 * v) * WW + cc;
    for (int i = 0; i < 32; ++i) {
#pragma unroll
        for (int k = 0; k < 4; ++k) {
            unsigned cnt = ((P0[k] >> i) & 1u) + (((P1[k] >> i) & 1u) << 1)
                         + (((P2[k] >> i) & 1u) << 2) + (((P3[k] >> i) & 1u) << 3);
            float p = sigf(pp[(size_t)(32 * k + i) * WW]);
            wsum += p * (float)cnt;
        }
    }

    float pw = wsum, pr = (float)rsum;
#pragma unroll
    for (int off = 32; off; off >>= 1) {
        pw += __shfl_down(pw, off, 64);
        pr += __shfl_down(pr, off, 64);
    }
    if (lane == 0) { partials[2 * wid] = pw; partials[2 * wid + 1] = pr; }
}

// 64-thread blocks (1 wave/block): float tasks = blocks 0..NF-1 -> exactly
// 10 float waves per CU under round-robin dispatch; bit tasks spread 3-4/CU.
__global__ __launch_bounds__(64)
void cld_main(const float* __restrict__ pred, const float* __restrict__ target,
              float* __restrict__ partials)
{
    const int wid  = blockIdx.x;
    const int lane = threadIdx.x;

    if (wid < NF) {
        // -------- float chain 0 (fp16x2 packed) --------
        int t_ = wid;
        const int b = t_ / (FSH * FSV);  t_ -= b * (FSH * FSV);
        const int u = t_ / FSV;
        const int v = t_ - u * FSV;
        const int r0 = v * RV;
        const int cbase = u * 102 - 12;
        const int UW = (u == FSH - 1) ? 104 : 102;

        const int c0 = cbase + 2 * lane;
        const int c1 = c0 + 1;
        const bool ok0 = (c0 >= 0) && (c0 < WW);
        const bool ok1 = (c1 >= 0) && (c1 < WW);
        const int wc0 = 2 * lane;
        const bool useX = (wc0     >= 12) && (wc0     < 12 + UW);
        const bool useY = (wc0 + 1 >= 12) && (wc0 + 1 < 12 + UW);
        // eclamp: ok -> -inf (no-op for hmax), OOB -> +inf (force erode pad)
        // dclamp: ok -> +inf (no-op for hmin), OOB -> -inf (force dilate pad)
        const unsigned elo = ok0 ? 0xFC00u : 0x7C00u;
        const unsigned ehi = ok1 ? 0xFC00u : 0x7C00u;
        const h2 eclamp = h2bits(elo | (ehi << 16));
        const h2 dclamp = h2bits((elo | (ehi << 16)) ^ 0x80008000u);
        const int cc = min(max(c0, 0), WW - 2);

        const float* ip = pred   + (size_t)b * HH * WW + (ptrdiff_t)(r0 - 11) * WW + cc;
        const float* wp = target + (size_t)b * HH * WW + (size_t)r0 * WW + cc;

        if (v == 0 || v == FSV - 1)
            do_strip<true >(ip, wp, r0, ok0, ok1, useX, useY, eclamp, dclamp, partials, wid, lane);
        else
            do_strip<false>(ip, wp, r0, ok0, ok1, useX, useY, eclamp, dclamp, partials, wid, lane);
    } else {
        // -------- bitwise chain 1 --------
        int idx = wid - NF;
        const int b = idx / (BSU * BSV);  idx -= b * (BSU * BSV);
        const int u = idx / BSV;
        const int v = idx - u * BSV;
        do_bits(target, pred, b, u, v, partials, wid, lane);
    }
}

// Deterministic final reduction + loss formula.
__global__ void cld_final(const float* __restrict__ partials, float* __restrict__ out)
{
    const int tid = threadIdx.x;
    double a0 = 0, a1 = 0, a2 = 0, a3 = 0;
    for (int i = tid; i < NF; i += 256) {
        a0 += (double)partials[2 * i];          // sum(target*skel_pred)
        a1 += (double)partials[2 * i + 1];      // sum(skel_pred)
    }
    for (int i = NF + tid; i < NTASK; i += 256) {
        a2 += (double)partials[2 * i];          // sum(p*skel_gt)
        a3 += (double)partials[2 * i + 1];      // sum(skel_gt)
    }
    __shared__ double red[256][4];
    red[tid][0] = a0; red[tid][1] = a1; red[tid][2] = a2; red[tid][3] = a3;
    __syncthreads();
    for (int s2 = 128; s2 > 0; s2 >>= 1) {
        if (tid < s2) {
            red[tid][0] += red[tid + s2][0]; red[tid][1] += red[tid + s2][1];
            red[tid][2] += red[tid + s2][2]; red[tid][3] += red[tid + s2][3];
        }
        __syncthreads();
    }
    if (tid == 0) {
        double tsens = red[0][0] / (red[0][1] + 1e-6);
        double tprec = red[0][2] / (red[0][3] + 1e-6);
        double cl = 2.0 * tprec * tsens / (tprec + tsens + 1e-6);
        out[0] = (float)(1.0 - cl);
    }
}

extern "C" void kernel_launch(void* const* d_in, const int* in_sizes, int n_in,
                              void* d_out, int out_size, void* d_ws, size_t ws_size,
                              hipStream_t stream) {
    const float* pred   = (const float*)d_in[0];
    const float* target = (const float*)d_in[1];
    float* out = (float*)d_out;
    float* partials = (float*)d_ws;            // NTASK*2 floats = ~27 KB

    hipLaunchKernelGGL(cld_main, dim3(NTASK), dim3(64), 0, stream,
                       pred, target, partials);
    hipLaunchKernelGGL(cld_final, dim3(1), dim3(256), 0, stream, partials, out);
}